// Round 2
// baseline (74.295 us; speedup 1.0000x reference)
//
#include <hip/hip_runtime.h>

// GraphUpSample: per-node Linear(3 -> 3*2) over 16 nodes + static column gather
// (the reference's aliased in-place permutation collapses to out col <- SRC[col]).
//
// Structure insight: for fixed output col, all 3 channels share node n = SRC[col]>>1
// and the same 3 inputs x[row][c'][n]; only the weight row o = 2c + (SRC[col]&1)
// differs. One thread per col => 12 weight regs, 3 loads -> 9 FMA -> 3 stores per row.
// x gathers are 64B-line-exact per half-wave; stores are full 128B aligned segments.

#define BATCH 8192
#define FEAT  64
#define BF_TOTAL (BATCH * FEAT)      // 524288 rows
#define ROWS_PER_BLOCK 64
#define THREADS 256                  // 32 cols x 8 row_subs

__constant__ int c_SRC[32] = {
    0, 2, 4, 6, 8, 10, 12, 14,
    1, 5, 9, 13, 3, 11, 7, 15,
    1, 3, 5, 7, 9, 11, 13, 15,
    3, 7, 11, 15, 7, 15, 15, 31
};

__global__ __launch_bounds__(THREADS)
void GraphUpSample_12120397709982_kernel(const float* __restrict__ x,
                                         const float* __restrict__ W,
                                         const float* __restrict__ bia,
                                         float* __restrict__ out)
{
    const int tid  = threadIdx.x;
    const int col  = tid & 31;           // output column within [0,32)
    const int rsub = tid >> 5;           // row sub-index 0..7
    const long long rowbase = (long long)blockIdx.x * ROWS_PER_BLOCK;

    const int s = c_SRC[col];
    const int n = s >> 1;                // source node, in {0..7,15}
    const int m = s & 1;

    // weights in registers: W[n][2c+m][c'], bias[n][2c+m]  (L1/L2-resident, tiny)
    float w[3][3], bb[3];
#pragma unroll
    for (int c = 0; c < 3; ++c) {
        const int o = 2 * c + m;
        const float* wp = W + (n * 6 + o) * 3;
        w[c][0] = wp[0]; w[c][1] = wp[1]; w[c][2] = wp[2];
        bb[c] = bia[n * 6 + o];
    }

    const float* xb = x   + rowbase * 48;
    float*       ob = out + rowbase * 96;

#pragma unroll
    for (int it = 0; it < ROWS_PER_BLOCK / 8; ++it) {
        const int row = it * 8 + rsub;
        // three line-exact gathers: each half-wave hits one 64B line
        const float x0 = __builtin_nontemporal_load(xb + row * 48 +      n);
        const float x1 = __builtin_nontemporal_load(xb + row * 48 + 16 + n);
        const float x2 = __builtin_nontemporal_load(xb + row * 48 + 32 + n);
#pragma unroll
        for (int c = 0; c < 3; ++c) {
            const float v = fmaf(x0, w[c][0],
                            fmaf(x1, w[c][1],
                            fmaf(x2, w[c][2], bb[c])));
            // half-wave writes one full, aligned 128B segment
            __builtin_nontemporal_store(v, ob + row * 96 + c * 32 + col);
        }
    }
}

extern "C" void kernel_launch(void* const* d_in, const int* in_sizes, int n_in,
                              void* d_out, int out_size, void* d_ws, size_t ws_size,
                              hipStream_t stream) {
    const float* x = (const float*)d_in[0];
    const float* W = (const float*)d_in[1];
    const float* b = (const float*)d_in[2];
    float* out = (float*)d_out;

    const int blocks = BF_TOTAL / ROWS_PER_BLOCK;  // 8192
    GraphUpSample_12120397709982_kernel<<<blocks, THREADS, 0, stream>>>(x, W, b, out);
}

// Round 3
// 65.937 us; speedup vs baseline: 1.1268x; 1.1268x over previous
//
#include <hip/hip_runtime.h>

// GraphUpSample: per-node Linear(3->6) over 16 nodes + static column gather
// (the reference's aliased in-place permutation collapses to out col <- SRC[col]).
//
// R3: thread owns 4 fixed output columns (fc0) for all 3 channels.
//  - weights/bias in 12 float4 REGISTERS (no LDS table -> no 12-way conflicts)
//  - x staged via coalesced float4 into LDS; per-row reads <=2-way aliased (free)
//  - float4 stores, same VMEM instruction count as R1

#define BATCH 8192
#define FEAT  64
#define BF_TOTAL (BATCH * FEAT)      // 524288 rows
#define ROWS_PER_BLOCK 64
#define THREADS 256                  // 8 col-groups x 32 row-slots, 2 rows/thread

__constant__ int c_SRC[32] = {
    0, 2, 4, 6, 8, 10, 12, 14,
    1, 5, 9, 13, 3, 11, 7, 15,
    1, 3, 5, 7, 9, 11, 13, 15,
    3, 7, 11, 15, 7, 15, 15, 31
};

__global__ __launch_bounds__(THREADS)
void GraphUpSample_12120397709982_kernel(const float* __restrict__ x,
                                         const float* __restrict__ W,
                                         const float* __restrict__ bia,
                                         float* __restrict__ out)
{
    __shared__ float xs[ROWS_PER_BLOCK * 48];    // 12 KiB, no table

    const int tid  = threadIdx.x;
    const int fc0  = tid & 7;        // column group: cols 4*fc0 .. 4*fc0+3
    const int rset = tid >> 3;       // 0..31 -> rows rset, rset+32
    const long long rowbase = (long long)blockIdx.x * ROWS_PER_BLOCK;

    // ---- stage x: 768 float4, fully coalesced ----
    const float4* xg  = (const float4*)(x + rowbase * 48);
    float4*       xsv = (float4*)xs;
#pragma unroll
    for (int j = 0; j < 3; ++j)
        xsv[tid + j * THREADS] = xg[tid + j * THREADS];

    // ---- weights into registers (overlaps staging; W/b tiny, L1/L2-resident) ----
    int   nn[4];
    float4 wr[3][4];                 // (w0,w1,w2,bias) per (channel, subcol)
#pragma unroll
    for (int s = 0; s < 4; ++s) {
        const int src = c_SRC[fc0 * 4 + s];
        const int n   = src >> 1;
        const int m   = src & 1;
        nn[s] = n;
#pragma unroll
        for (int c = 0; c < 3; ++c) {
            const int o = 2 * c + m;
            const float* wp = W + (n * 6 + o) * 3;
            wr[c][s] = make_float4(wp[0], wp[1], wp[2], bia[n * 6 + o]);
        }
    }
    __syncthreads();

    float4* og = (float4*)(out + rowbase * 96);
#pragma unroll
    for (int rr = 0; rr < 2; ++rr) {
        const int row = rset + rr * 32;
        const float* xr = xs + row * 48;

        float xv[3][4];
#pragma unroll
        for (int cp = 0; cp < 3; ++cp)
#pragma unroll
            for (int s = 0; s < 4; ++s)
                xv[cp][s] = xr[cp * 16 + nn[s]];   // <=2-way bank alias: free

#pragma unroll
        for (int c = 0; c < 3; ++c) {
            float4 o4;
            o4.x = fmaf(xv[0][0], wr[c][0].x, fmaf(xv[1][0], wr[c][0].y, fmaf(xv[2][0], wr[c][0].z, wr[c][0].w)));
            o4.y = fmaf(xv[0][1], wr[c][1].x, fmaf(xv[1][1], wr[c][1].y, fmaf(xv[2][1], wr[c][1].z, wr[c][1].w)));
            o4.z = fmaf(xv[0][2], wr[c][2].x, fmaf(xv[1][2], wr[c][2].y, fmaf(xv[2][2], wr[c][2].z, wr[c][2].w)));
            o4.w = fmaf(xv[0][3], wr[c][3].x, fmaf(xv[1][3], wr[c][3].y, fmaf(xv[2][3], wr[c][3].z, wr[c][3].w)));
            og[row * 24 + c * 8 + fc0] = o4;       // full 128B segments per 8 lanes
        }
    }
}

extern "C" void kernel_launch(void* const* d_in, const int* in_sizes, int n_in,
                              void* d_out, int out_size, void* d_ws, size_t ws_size,
                              hipStream_t stream) {
    const float* x = (const float*)d_in[0];
    const float* W = (const float*)d_in[1];
    const float* b = (const float*)d_in[2];
    float* out = (float*)d_out;

    const int blocks = BF_TOTAL / ROWS_PER_BLOCK;  // 8192
    GraphUpSample_12120397709982_kernel<<<blocks, THREADS, 0, stream>>>(x, W, b, out);
}

// Round 4
// 57.182 us; speedup vs baseline: 1.2993x; 1.1531x over previous
//
#include <hip/hip_runtime.h>

// GraphUpSample: per-node Linear(3->6) over 16 nodes + static column gather
// (the reference's aliased in-place column loop collapses to out col <- SRC[col]).
//
// R4 = R1's low-VMEM shape + R3's low-LDS compute:
//  - weight table built once/block in LDS by 96 threads (cheap, as in R1),
//    then pulled into 12 float4 REGISTERS per thread (12 ds_read_b128, once)
//  - x staged coalesced into LDS with rows padded to 52 floats -> <=2-way banks
//  - tbl padded to stride 5 float4 (bank stride 20) -> conflict-free reads
//  - compute loop: 12 ds_read_b32 per row per thread, float4 stores

#define BATCH 8192
#define FEAT  64
#define BF_TOTAL (BATCH * FEAT)      // 524288 rows
#define ROWS_PER_BLOCK 64
#define THREADS 256                  // 8 col-groups x 32 row-slots, 2 rows/thread
#define XROW 13                      // float4 per padded x row (52 floats)

__constant__ int c_SRC[32] = {
    0, 2, 4, 6, 8, 10, 12, 14,
    1, 5, 9, 13, 3, 11, 7, 15,
    1, 3, 5, 7, 9, 11, 13, 15,
    3, 7, 11, 15, 7, 15, 15, 31
};

__global__ __launch_bounds__(THREADS)
void GraphUpSample_12120397709982_kernel(const float* __restrict__ x,
                                         const float* __restrict__ W,
                                         const float* __restrict__ bia,
                                         float* __restrict__ out)
{
    __shared__ float4 xs4[ROWS_PER_BLOCK * XROW];   // 13312 B
    __shared__ float4 tbl4[3 * 8 * 5];              // 1920 B, stride-5 padded
    __shared__ int    nns[32];

    const int tid  = threadIdx.x;
    const int fc0  = tid & 7;        // column group: cols 4*fc0 .. 4*fc0+3
    const int rset = tid >> 3;       // 0..31 -> rows rset, rset+32
    const long long rowbase = (long long)blockIdx.x * ROWS_PER_BLOCK;

    // ---- stage x: 768 float4 coalesced, rows padded to 13 float4 ----
    const float4* xg = (const float4*)(x + rowbase * 48);
#pragma unroll
    for (int j = 0; j < 3; ++j) {
        const int p   = tid + j * THREADS;   // 0..767
        const int row = p / 12;
        const int k   = p - row * 12;
        xs4[row * XROW + k] = xg[p];
    }

    // ---- build weight table once per block (96 threads, tiny) ----
    if (tid < 96) {
        const int c   = tid >> 5;
        const int col = tid & 31;
        const int f   = col >> 2;
        const int s   = col & 3;
        const int src = c_SRC[col];
        const int n   = src >> 1;
        const int o   = 2 * c + (src & 1);
        const float* wp = W + (n * 6 + o) * 3;
        tbl4[(c * 8 + f) * 5 + s] = make_float4(wp[0], wp[1], wp[2], bia[n * 6 + o]);
    }
    if (tid < 32) nns[tid] = c_SRC[tid] >> 1;
    __syncthreads();

    // ---- weights -> registers: 12 ds_read_b128 + 4 ds_read_b32, once ----
    int nn[4];
#pragma unroll
    for (int s = 0; s < 4; ++s) nn[s] = nns[fc0 * 4 + s];
    float4 wr[3][4];
#pragma unroll
    for (int c = 0; c < 3; ++c)
#pragma unroll
        for (int s = 0; s < 4; ++s)
            wr[c][s] = tbl4[(c * 8 + fc0) * 5 + s];

    const float* xs = (const float*)xs4;
    float4* og = (float4*)(out + rowbase * 96);
#pragma unroll
    for (int rr = 0; rr < 2; ++rr) {
        const int row = rset + rr * 32;
        const float* xr = xs + row * (XROW * 4);

        float xv[3][4];
#pragma unroll
        for (int cp = 0; cp < 3; ++cp)
#pragma unroll
            for (int s = 0; s < 4; ++s)
                xv[cp][s] = xr[cp * 16 + nn[s]];   // padded rows: <=2-way, free

#pragma unroll
        for (int c = 0; c < 3; ++c) {
            float4 o4;
            o4.x = fmaf(xv[0][0], wr[c][0].x, fmaf(xv[1][0], wr[c][0].y, fmaf(xv[2][0], wr[c][0].z, wr[c][0].w)));
            o4.y = fmaf(xv[0][1], wr[c][1].x, fmaf(xv[1][1], wr[c][1].y, fmaf(xv[2][1], wr[c][1].z, wr[c][1].w)));
            o4.z = fmaf(xv[0][2], wr[c][2].x, fmaf(xv[1][2], wr[c][2].y, fmaf(xv[2][2], wr[c][2].z, wr[c][2].w)));
            o4.w = fmaf(xv[0][3], wr[c][3].x, fmaf(xv[1][3], wr[c][3].y, fmaf(xv[2][3], wr[c][3].z, wr[c][3].w)));
            og[row * 24 + c * 8 + fc0] = o4;       // full 128B segments per 8 lanes
        }
    }
}

extern "C" void kernel_launch(void* const* d_in, const int* in_sizes, int n_in,
                              void* d_out, int out_size, void* d_ws, size_t ws_size,
                              hipStream_t stream) {
    const float* x = (const float*)d_in[0];
    const float* W = (const float*)d_in[1];
    const float* b = (const float*)d_in[2];
    float* out = (float*)d_out;

    const int blocks = BF_TOTAL / ROWS_PER_BLOCK;  // 8192
    GraphUpSample_12120397709982_kernel<<<blocks, THREADS, 0, stream>>>(x, W, b, out);
}